// Round 3
// baseline (3612.218 us; speedup 1.0000x reference)
//
#include <hip/hip_runtime.h>
#include <math.h>

#define PP 128
#define DD 128
#define RR 16384
#define RR2 32768          /* floats per f-row of a plane (RR complex) */
#define EE 131072
#define TT 1024
#define FF 513
#define FPAD 576           /* padded f rows so matmul tiles of 64 need no guards */

#define TAU_SCALE 46.64723032069971    /* SR / C_SOUND */
#define KDECAY   -0.0211392282f        /* LOG_GAMMA/C - AIR */
#define LOG_GAMMA -6.907755278982137f
#define TWO_PI    6.283185307179586

#define FMA4(A, K, V) { A.x = fmaf(K, V.x, A.x); A.y = fmaf(K, V.y, A.y); \
                        A.z = fmaf(K, V.z, A.z); A.w = fmaf(K, V.w, A.w); }

__device__ __forceinline__ void pf_sincos(float tau, int f, float* s, float* c) {
    // phase = exp(-2*pi*i * tau * f / T); reduce in double, eval in float
    double rev = (double)tau * (double)f * (1.0 / 1024.0);
    rev -= floor(rev);
    float ang = (float)(-TWO_PI * rev);
    __sincosf(ang, s, c);
}

// ---- per-row precompute: amp_src, tau_src, amp_rec, tau_rec, dec_prop, tau_prop
__global__ void k_per_row(const float* __restrict__ rpos,
                          const float* __restrict__ spos,
                          const float* __restrict__ cpos,
                          const float* __restrict__ avg_dist,
                          float* __restrict__ per_row) {
    int r = blockIdx.x * blockDim.x + threadIdx.x;
    if (r >= RR) return;
    float x = rpos[3*r], y = rpos[3*r+1], z = rpos[3*r+2];

    float dx = x - spos[0], dy = y - spos[1], dz = z - spos[2];
    float ds = sqrtf(dx*dx + dy*dy + dz*dz);
    per_row[0*RR + r] = (1.0f/(ds*ds + 0.001f)) * expf(KDECAY * ds);
    per_row[1*RR + r] = ds * (float)TAU_SCALE;

    dx = x - cpos[0]; dy = y - cpos[1]; dz = z - cpos[2];
    float dr = sqrtf(dx*dx + dy*dy + dz*dz);
    per_row[2*RR + r] = (1.0f/(dr*dr + 0.001f)) * expf(KDECAY * dr);
    per_row[3*RR + r] = dr * (float)TAU_SCALE;

    float da = avg_dist[r];
    per_row[4*RR + r] = expf(KDECAY * da);
    per_row[5*RR + r] = da * (float)TAU_SCALE;
}

// ---- K[p][d][e] = c0[p]*basis0[d][e] + c1[p]*basis1[d][e]
__global__ void k_build_K(const float* __restrict__ absorption,
                          const float* __restrict__ scattering,
                          const int* __restrict__ object_ids,
                          const float* __restrict__ basis,
                          float* __restrict__ Kmat) {
    int idx = blockIdx.x * 256 + threadIdx.x;   // < P*D*D
    int p  = idx >> 14;
    int de = idx & 16383;
    int obj = object_ids[p];
    float refl = 1.0f - absorption[obj];
    float sc   = scattering[obj];
    Kmat[idx] = refl*sc*basis[de] + refl*(1.0f - sc)*basis[16384 + de];
}

// ---- CSR build
__global__ void k_count(const int* __restrict__ gk_row, int* __restrict__ counts) {
    int e = blockIdx.x * 256 + threadIdx.x;
    atomicAdd(&counts[gk_row[e]], 1);
}

__global__ __launch_bounds__(1024) void k_scan(const int* __restrict__ counts,
                                               int* __restrict__ row_start,
                                               int* __restrict__ cursor) {
    __shared__ int sh[1024];
    int tid = threadIdx.x;
    int base = tid * 16;
    int local[16];
    int sum = 0;
    #pragma unroll
    for (int j = 0; j < 16; j++) { local[j] = sum; sum += counts[base + j]; }
    sh[tid] = sum;
    __syncthreads();
    for (int off = 1; off < 1024; off <<= 1) {
        int v = (tid >= off) ? sh[tid - off] : 0;
        __syncthreads();
        sh[tid] += v;
        __syncthreads();
    }
    int chunk_excl = sh[tid] - sum;   // exclusive prefix of this 16-chunk
    #pragma unroll
    for (int j = 0; j < 16; j++) {
        int v = chunk_excl + local[j];
        row_start[base + j] = v;
        cursor[base + j] = v;
    }
    if (tid == 1023) row_start[RR] = chunk_excl + sum;
}

// scatter packing {col, val} per edge -> one b64 load in segsum
__global__ void k_scatter(const int* __restrict__ gk_row,
                          const float* __restrict__ gk_val,
                          const int* __restrict__ gk_col,
                          int* __restrict__ cursor,
                          int2* __restrict__ edge) {
    int e = blockIdx.x * 256 + threadIdx.x;
    int pos = atomicAdd(&cursor[gk_row[e]], 1);
    edge[pos] = make_int2(gk_col[e], __float_as_int(gk_val[e]));
}

__device__ __forceinline__ void block_reduce_store(float2 esum, float* echo, int f, bool assign) {
    for (int off = 32; off >= 1; off >>= 1) {
        esum.x += __shfl_down(esum.x, off, 64);
        esum.y += __shfl_down(esum.y, off, 64);
    }
    __shared__ float2 red[8];
    int lane = threadIdx.x & 63, wid = threadIdx.x >> 6;
    if (lane == 0) red[wid] = esum;
    __syncthreads();
    if (threadIdx.x == 0) {
        float sx = 0.f, sy = 0.f;
        #pragma unroll
        for (int i = 0; i < 8; i++) { sx += red[i].x; sy += red[i].y; }
        if (assign) { echo[2*f] = sx;  echo[2*f+1] = sy; }
        else        { echo[2*f] += sx; echo[2*f+1] += sy; }
    }
}

// ---- init: cur[f][row] = amp_src*phase(tau_src); echo[f] = rad's receiver sum
__global__ __launch_bounds__(512) void k_init(const float* __restrict__ per_row,
                                              float* __restrict__ cur_cc,
                                              float* __restrict__ echo) {
    int f = blockIdx.x;            // 0..FF-1
    float2 esum = make_float2(0.f, 0.f);
    float* win = cur_cc + (size_t)f * RR2;
    for (int r = threadIdx.x; r < RR; r += 512) {
        float amp = per_row[r], tau = per_row[RR + r];
        float s, c; pf_sincos(tau, f, &s, &c);
        float re = amp * c, im = amp * s;
        *(float2*)(win + r * 2) = make_float2(re, im);
        float w = per_row[2*RR + r], taur = per_row[3*RR + r];
        float s2, c2; pf_sincos(taur, f, &s2, &c2);
        esum.x += w * (c2*re - s2*im);
        esum.y += w * (c2*im + s2*re);
    }
    block_reduce_store(esum, echo, f, true);
}

// ---- matmul + prop: out[f][p*128+d] = prop(row,f) * sum_e K[p,d,e]*in[f][p*128+e]
// grid (9, 128): x = 64-f tile, y = patch. K^T staged in LDS (stride 129,
// conflict-free); per 8-f group the input vectors staged as float4 f-pairs.
__global__ __launch_bounds__(256) void k_matmul(const float* __restrict__ Kmat,
                                                const float* __restrict__ in_cc,
                                                const float* __restrict__ per_row,
                                                float* __restrict__ out_cc) {
    __shared__ float Klds[128 * 129];
    __shared__ float4 vlds[4][128];
    int p = blockIdx.y;
    int tid = threadIdx.x;
    const float* Kp = Kmat + (p << 14);
    for (int i = tid; i < 16384; i += 256)
        Klds[(i & 127) * 129 + (i >> 7)] = Kp[i];   // Klds[e*129+d]

    int fslot = tid >> 7, d = tid & 127;
    int row = (p << 7) + d;
    float dec = per_row[4*RR + row];
    float tau = per_row[5*RR + row];
    int rbase2 = ((p << 7)) * 2;

    for (int g = 0; g < 8; g++) {
        int f0 = (blockIdx.x << 6) + (g << 3);
        __syncthreads();
        for (int i = tid; i < 512; i += 256) {
            int fp = i >> 7, e = i & 127;
            int fa = f0 + 2*fp;
            float2 va = *(const float2*)(in_cc + (size_t)fa * RR2 + rbase2 + e*2);
            float2 vb = *(const float2*)(in_cc + (size_t)(fa+1) * RR2 + rbase2 + e*2);
            vlds[fp][e] = make_float4(va.x, va.y, vb.x, vb.y);
        }
        __syncthreads();
        float4 acc0 = make_float4(0.f,0.f,0.f,0.f);
        float4 acc1 = make_float4(0.f,0.f,0.f,0.f);
        int fp0 = fslot << 1;
        #pragma unroll 4
        for (int e = 0; e < 128; e++) {
            float kv = Klds[e * 129 + d];
            float4 v0 = vlds[fp0][e];
            float4 v1 = vlds[fp0 + 1][e];
            FMA4(acc0, kv, v0);
            FMA4(acc1, kv, v1);
        }
        int fb = f0 + (fslot << 2);
        float s0,c0,s1,c1,s2,c2,s3,c3;
        pf_sincos(tau, fb,   &s0, &c0);
        pf_sincos(tau, fb+1, &s1, &c1);
        pf_sincos(tau, fb+2, &s2, &c2);
        pf_sincos(tau, fb+3, &s3, &c3);
        size_t o = (size_t)fb * RR2 + row * 2;
        *(float2*)(out_cc + o)         = make_float2(dec*(acc0.x*c0 - acc0.y*s0), dec*(acc0.y*c0 + acc0.x*s0));
        *(float2*)(out_cc + o +   RR2) = make_float2(dec*(acc0.z*c1 - acc0.w*s1), dec*(acc0.w*c1 + acc0.z*s1));
        *(float2*)(out_cc + o + 2*RR2) = make_float2(dec*(acc1.x*c2 - acc1.y*s2), dec*(acc1.y*c2 + acc1.x*s2));
        *(float2*)(out_cc + o + 3*RR2) = make_float2(dec*(acc1.z*c3 - acc1.w*s3), dec*(acc1.w*c3 + acc1.z*s3));
    }
}

// ---- segment sum, one block per f: gather window in[f][*] is a contiguous
// 128 KiB slice (L2-resident). Fused receiver-echo epilogue, single writer per f.
__global__ __launch_bounds__(512) void k_segsum(const int* __restrict__ row_start,
                                                const int2* __restrict__ edge,
                                                const float* __restrict__ in_cc,
                                                float* __restrict__ cur_cc,
                                                const float* __restrict__ per_row,
                                                float* __restrict__ echo,
                                                int store_cur) {
    int f = blockIdx.x;
    const float* win = in_cc + (size_t)f * RR2;
    float* wout = cur_cc + (size_t)f * RR2;
    float2 esum = make_float2(0.f, 0.f);
    for (int r = threadIdx.x; r < RR; r += 512) {
        int s0 = row_start[r], s1 = row_start[r + 1];
        float ar = 0.f, ai = 0.f;
        for (int k = s0; k < s1; k++) {
            int2 ed = edge[k];
            float v = __int_as_float(ed.y);
            float2 g = *(const float2*)(win + ed.x * 2);
            ar = fmaf(v, g.x, ar);
            ai = fmaf(v, g.y, ai);
        }
        if (store_cur) *(float2*)(wout + r * 2) = make_float2(ar, ai);
        float w = per_row[2*RR + r], taur = per_row[3*RR + r];
        float s, c; pf_sincos(taur, f, &s, &c);
        esum.x += w * (c*ar - s*ai);
        esum.y += w * (c*ai + s*ar);
    }
    block_reduce_store(esum, echo, f, false);
}

// ---- irfft(n=1024) / fsm_window
__global__ void k_irfft(const float* __restrict__ echo, float* __restrict__ out) {
    int t = blockIdx.x * blockDim.x + threadIdx.x;   // 0..1023
    float acc = echo[0];                              // f=0 (real)
    float nyq = echo[2 * 512];                        // Nyquist real part
    acc += (t & 1) ? -nyq : nyq;
    for (int f = 1; f < 512; f++) {
        int m = (f * t) & 1023;
        float ang = (float)m * 0.006135923151542565f;  // 2*pi/1024
        float s, c; __sincosf(ang, &s, &c);
        acc += 2.0f * (echo[2*f]*c - echo[2*f+1]*s);
    }
    acc *= (1.0f / 1024.0f);
    float tsec = (float)t * (1.0f / 16000.0f);
    float win = expf(LOG_GAMMA * tsec);
    out[t] = acc / win;
}

extern "C" void kernel_launch(void* const* d_in, const int* in_sizes, int n_in,
                              void* d_out, int out_size, void* d_ws, size_t ws_size,
                              hipStream_t stream) {
    const float* source_pos   = (const float*)d_in[0];
    const float* receiver_pos = (const float*)d_in[1];
    const float* absorption   = (const float*)d_in[2];
    const float* scattering   = (const float*)d_in[3];
    const float* gk_val       = (const float*)d_in[4];
    const float* basis        = (const float*)d_in[5];
    const float* avg_dist     = (const float*)d_in[6];
    const float* rpos         = (const float*)d_in[7];
    const int*   gk_row       = (const int*)d_in[8];
    const int*   gk_col       = (const int*)d_in[9];
    const int*   object_ids   = (const int*)d_in[10];
    float* out = (float*)d_out;

    char* base = (char*)d_ws;
    size_t off = 0;
    auto alloc = [&](size_t bytes) -> void* {
        void* ptr = base + off;
        off = (off + bytes + 255) & ~(size_t)255;
        return ptr;
    };
    const size_t PLANE = (size_t)FPAD * RR2;   // transposed complex plane [f][row]
    float* Kmat      = (float*)alloc(sizeof(float) * PP * DD * DD);
    float* cur_cc    = (float*)alloc(sizeof(float) * PLANE);
    float* nxt_cc    = (float*)alloc(sizeof(float) * PLANE);
    float* per_row   = (float*)alloc(sizeof(float) * 6 * RR);
    int*   counts    = (int*)alloc(sizeof(int) * RR);
    int*   row_start = (int*)alloc(sizeof(int) * (RR + 1));
    int*   cursor    = (int*)alloc(sizeof(int) * RR);
    int2*  edge      = (int2*)alloc(sizeof(int2) * EE);
    float* echo      = (float*)alloc(sizeof(float) * 1040);

    hipMemsetAsync(counts, 0, sizeof(int) * RR, stream);

    k_per_row<<<RR / 256, 256, 0, stream>>>(rpos, source_pos, receiver_pos, avg_dist, per_row);
    k_build_K<<<(PP * DD * DD) / 256, 256, 0, stream>>>(absorption, scattering, object_ids, basis, Kmat);
    k_count<<<EE / 256, 256, 0, stream>>>(gk_row, counts);
    k_scan<<<1, 1024, 0, stream>>>(counts, row_start, cursor);
    k_scatter<<<EE / 256, 256, 0, stream>>>(gk_row, gk_val, gk_col, cursor, edge);
    k_init<<<FF, 512, 0, stream>>>(per_row, cur_cc, echo);

    for (int b = 0; b < 4; b++) {
        k_matmul<<<dim3(9, PP), 256, 0, stream>>>(Kmat, cur_cc, per_row, nxt_cc);
        k_segsum<<<FF, 512, 0, stream>>>(row_start, edge, nxt_cc, cur_cc,
                                         per_row, echo, (b < 3) ? 1 : 0);
    }

    k_irfft<<<4, 256, 0, stream>>>(echo, out);
}

// Round 4
// 1077.982 us; speedup vs baseline: 3.3509x; 3.3509x over previous
//
#include <hip/hip_runtime.h>
#include <math.h>

#define PP 128
#define DD 128
#define RR 16384
#define EE 131072
#define TT 1024
#define FF 513
#define FP 520          /* padded f count */
#define FP2 1040        /* floats per row (interleaved complex) */
#define KSTRIDE 132     /* LDS row stride for K tile: 16B-aligned, conflict-free */

#define TAU_SCALE 46.64723032069971    /* SR / C_SOUND */
#define KDECAY   -0.0211392282f        /* LOG_GAMMA/C - AIR */
#define LOG_GAMMA -6.907755278982137f
#define TWO_PI    6.283185307179586

__device__ __forceinline__ void pf_sincos(float tau, int f, float* s, float* c) {
    // phase = exp(-2*pi*i * tau * f / T); reduce in double, eval in float
    double rev = (double)tau * (double)f * (1.0 / 1024.0);
    rev -= floor(rev);
    float ang = (float)(-TWO_PI * rev);
    __sincosf(ang, s, c);
}

// ---- per-row precompute: amp_src, tau_src, amp_rec, tau_rec, dec_prop, tau_prop
__global__ void k_per_row(const float* __restrict__ rpos,
                          const float* __restrict__ spos,
                          const float* __restrict__ cpos,
                          const float* __restrict__ avg_dist,
                          float* __restrict__ per_row) {
    int r = blockIdx.x * blockDim.x + threadIdx.x;
    if (r >= RR) return;
    float x = rpos[3*r], y = rpos[3*r+1], z = rpos[3*r+2];

    float dx = x - spos[0], dy = y - spos[1], dz = z - spos[2];
    float ds = sqrtf(dx*dx + dy*dy + dz*dz);
    per_row[0*RR + r] = (1.0f/(ds*ds + 0.001f)) * expf(KDECAY * ds);
    per_row[1*RR + r] = ds * (float)TAU_SCALE;

    dx = x - cpos[0]; dy = y - cpos[1]; dz = z - cpos[2];
    float dr = sqrtf(dx*dx + dy*dy + dz*dz);
    per_row[2*RR + r] = (1.0f/(dr*dr + 0.001f)) * expf(KDECAY * dr);
    per_row[3*RR + r] = dr * (float)TAU_SCALE;

    float da = avg_dist[r];
    per_row[4*RR + r] = expf(KDECAY * da);
    per_row[5*RR + r] = da * (float)TAU_SCALE;
}

// ---- Kt[p][e][d] = refl*sc*basis0[d][e] + refl*(1-sc)*basis1[d][e]  (transposed)
__global__ void k_build_Kt(const float* __restrict__ absorption,
                           const float* __restrict__ scattering,
                           const int* __restrict__ object_ids,
                           const float* __restrict__ basis,
                           float* __restrict__ Kt) {
    int idx = blockIdx.x * 256 + threadIdx.x;   // p*16384 + e*128 + d
    int p = idx >> 14;
    int e = (idx >> 7) & 127;
    int d = idx & 127;
    int obj = object_ids[p];
    float refl = 1.0f - absorption[obj];
    float sc   = scattering[obj];
    int de = d * 128 + e;
    Kt[idx] = refl*sc*basis[de] + refl*(1.0f - sc)*basis[16384 + de];
}

// ---- CSR build
__global__ void k_count(const int* __restrict__ gk_row, int* __restrict__ counts) {
    int e = blockIdx.x * 256 + threadIdx.x;
    atomicAdd(&counts[gk_row[e]], 1);
}

__global__ __launch_bounds__(1024) void k_scan(const int* __restrict__ counts,
                                               int* __restrict__ row_start,
                                               int* __restrict__ cursor) {
    __shared__ int sh[1024];
    int tid = threadIdx.x;
    int base = tid * 16;
    int local[16];
    int sum = 0;
    #pragma unroll
    for (int j = 0; j < 16; j++) { local[j] = sum; sum += counts[base + j]; }
    sh[tid] = sum;
    __syncthreads();
    for (int off = 1; off < 1024; off <<= 1) {
        int v = (tid >= off) ? sh[tid - off] : 0;
        __syncthreads();
        sh[tid] += v;
        __syncthreads();
    }
    int chunk_excl = sh[tid] - sum;   // exclusive prefix of this 16-chunk
    #pragma unroll
    for (int j = 0; j < 16; j++) {
        int v = chunk_excl + local[j];
        row_start[base + j] = v;
        cursor[base + j] = v;
    }
    if (tid == 1023) row_start[RR] = chunk_excl + sum;
}

// scatter packing {col, val} per edge -> one b64 load in segsum
__global__ void k_scatter(const int* __restrict__ gk_row,
                          const float* __restrict__ gk_val,
                          const int* __restrict__ gk_col,
                          int* __restrict__ cursor,
                          int2* __restrict__ edge) {
    int e = blockIdx.x * 256 + threadIdx.x;
    int pos = atomicAdd(&cursor[gk_row[e]], 1);
    edge[pos] = make_int2(gk_col[e], __float_as_int(gk_val[e]));
}

// ---- init: cur[r][f] = amp_src*phase(tau_src); fused rad receiver-echo
__global__ __launch_bounds__(256) void k_init(const float* __restrict__ per_row,
                                              float* __restrict__ cur,
                                              float* __restrict__ echo) {
    int fl = threadIdx.x & 63, rg = threadIdx.x >> 6;
    int f = blockIdx.x * 64 + fl;               // < 576
    float ar = 0.f, ai = 0.f;
    int r0 = blockIdx.y * 512;
    if (f < FP) {
        for (int k = rg; k < 512; k += 4) {
            int r = r0 + k;
            float amp = per_row[r], tau = per_row[RR + r];
            float s, c; pf_sincos(tau, f, &s, &c);
            float re = amp * c, im = amp * s;
            *(float2*)(cur + (size_t)r * FP2 + f * 2) = make_float2(re, im);
            if (f < FF) {
                float w = per_row[2*RR + r], taur = per_row[3*RR + r];
                float s2, c2; pf_sincos(taur, f, &s2, &c2);
                ar = fmaf(w, c2*re - s2*im, ar);
                ai = fmaf(w, c2*im + s2*re, ai);
            }
        }
    }
    __shared__ float sh[4][64][2];
    sh[rg][fl][0] = ar; sh[rg][fl][1] = ai;
    __syncthreads();
    if (rg == 0 && f < FF) {
        float sx = sh[0][fl][0]+sh[1][fl][0]+sh[2][fl][0]+sh[3][fl][0];
        float sy = sh[0][fl][1]+sh[1][fl][1]+sh[2][fl][1]+sh[3][fl][1];
        atomicAdd(&echo[2*f],   sx);
        atomicAdd(&echo[2*f+1], sy);
    }
}

// ---- matmul + prop: out[p*128+d][f] = prop * sum_e Kt[p][e][d] * in[p*128+e][f]
// 1-D grid 2176 = 128 p x 17 ftiles(32 f), XCD-swizzled so one patch's K tile
// stays on one XCD's L2. 256 thr = 16 dg(8 d) x 16 fp(2 complex f).
// Inner loop per e: 2 LDS b128 (conflict-free, fp-broadcast) + 1 global dwordx4
// + 32 VALU FMA -> VALU-bound.
__global__ __launch_bounds__(256) void k_matmul(const float* __restrict__ Kt,
                                                const float* __restrict__ in,
                                                const float* __restrict__ per_row,
                                                float* __restrict__ out) {
    __shared__ float Klds[128 * KSTRIDE];   // [e][d]
    int b = blockIdx.x;
    int xcd = b & 7;
    int g = b >> 3;                 // 272 groups
    int p = (g / 17) * 8 + xcd;
    int ftile = g % 17;
    int tid = threadIdx.x;
    const float* Kp = Kt + (p << 14);
    for (int i = tid; i < 16384; i += 256)
        Klds[(i >> 7) * KSTRIDE + (i & 127)] = Kp[i];
    __syncthreads();

    int fp = tid & 15;              // f-pair
    int dg = tid >> 4;              // 8-d group
    int f = (ftile << 5) + (fp << 1);
    const float* vbase = in + (size_t)(p << 7) * FP2 + f * 2;
    float acc[8][4];
    #pragma unroll
    for (int j = 0; j < 8; j++) { acc[j][0]=0.f; acc[j][1]=0.f; acc[j][2]=0.f; acc[j][3]=0.f; }
    const float* kbase = Klds + (dg << 3);
    #pragma unroll 4
    for (int e = 0; e < 128; e++) {
        float4 v = *(const float4*)(vbase + (size_t)e * FP2);
        const float* kr = kbase + e * KSTRIDE;
        #pragma unroll
        for (int j = 0; j < 8; j++) {
            float kv = kr[j];
            acc[j][0] = fmaf(kv, v.x, acc[j][0]);
            acc[j][1] = fmaf(kv, v.y, acc[j][1]);
            acc[j][2] = fmaf(kv, v.z, acc[j][2]);
            acc[j][3] = fmaf(kv, v.w, acc[j][3]);
        }
    }
    if (f < FP) {                   // f<=518: stores f, f+1 both valid
        int d0 = dg << 3;
        #pragma unroll
        for (int j = 0; j < 8; j++) {
            int row = (p << 7) + d0 + j;
            float dec = per_row[4*RR + row];
            float tau = per_row[5*RR + row];
            float s0,c0,s1,c1;
            pf_sincos(tau, f,   &s0, &c0);
            pf_sincos(tau, f+1, &s1, &c1);
            float4 o;
            o.x = dec*(acc[j][0]*c0 - acc[j][1]*s0);
            o.y = dec*(acc[j][1]*c0 + acc[j][0]*s0);
            o.z = dec*(acc[j][2]*c1 - acc[j][3]*s1);
            o.w = dec*(acc[j][3]*c1 + acc[j][2]*s1);
            *(float4*)(out + (size_t)row * FP2 + f * 2) = o;
        }
    }
}

// ---- segment sum: cur[row][f] = sum_edges val*in[col][f]. 2 rows/block,
// 256 f-lanes, edges read once, 3 f-slices per edge (f, f+256, f+512<520).
__global__ __launch_bounds__(512) void k_segsum(const int* __restrict__ row_start,
                                                const int2* __restrict__ edge,
                                                const float* __restrict__ in,
                                                float* __restrict__ outp) {
    int ry = threadIdx.x >> 8;
    int row = (blockIdx.x << 1) + ry;
    int ft = threadIdx.x & 255;
    int s0 = row_start[row], s1 = row_start[row + 1];
    float a0r=0.f, a0i=0.f, a1r=0.f, a1i=0.f, a2r=0.f, a2i=0.f;
    bool has2 = (ft < 8);           // f2 = ft+512 < 520
    for (int t = s0; t < s1; t++) {
        int2 ed = edge[t];
        float v = __int_as_float(ed.y);
        const float* grow = in + (size_t)ed.x * FP2 + ft * 2;
        float2 g0 = *(const float2*)(grow);
        float2 g1 = *(const float2*)(grow + 512);
        a0r = fmaf(v, g0.x, a0r); a0i = fmaf(v, g0.y, a0i);
        a1r = fmaf(v, g1.x, a1r); a1i = fmaf(v, g1.y, a1i);
        if (has2) {
            float2 g2 = *(const float2*)(grow + 1024);
            a2r = fmaf(v, g2.x, a2r); a2i = fmaf(v, g2.y, a2i);
        }
    }
    float* wout = outp + (size_t)row * FP2 + ft * 2;
    *(float2*)(wout)       = make_float2(a0r, a0i);
    *(float2*)(wout + 512) = make_float2(a1r, a1i);
    if (has2) *(float2*)(wout + 1024) = make_float2(a2r, a2i);
}

// ---- per-bounce receiver reduction: echo[f] += sum_r w*phase(taur,f)*cur[r][f]
__global__ __launch_bounds__(256) void k_reduce(const float* __restrict__ plane,
                                                const float* __restrict__ per_row,
                                                float* __restrict__ echo) {
    int fl = threadIdx.x & 63, rg = threadIdx.x >> 6;
    int f = blockIdx.x * 64 + fl;
    bool act = (f < FF);
    float ar = 0.f, ai = 0.f;
    int r0 = blockIdx.y * 512;
    if (act) {
        for (int k = rg; k < 512; k += 4) {
            int r = r0 + k;
            float2 v = *(const float2*)(plane + (size_t)r * FP2 + f * 2);
            float w = per_row[2*RR + r], taur = per_row[3*RR + r];
            float s, c; pf_sincos(taur, f, &s, &c);
            ar = fmaf(w, c*v.x - s*v.y, ar);
            ai = fmaf(w, c*v.y + s*v.x, ai);
        }
    }
    __shared__ float sh[4][64][2];
    sh[rg][fl][0] = ar; sh[rg][fl][1] = ai;
    __syncthreads();
    if (rg == 0 && act) {
        float sx = sh[0][fl][0]+sh[1][fl][0]+sh[2][fl][0]+sh[3][fl][0];
        float sy = sh[0][fl][1]+sh[1][fl][1]+sh[2][fl][1]+sh[3][fl][1];
        atomicAdd(&echo[2*f],   sx);
        atomicAdd(&echo[2*f+1], sy);
    }
}

// ---- irfft(n=1024) / fsm_window
__global__ void k_irfft(const float* __restrict__ echo, float* __restrict__ out) {
    int t = blockIdx.x * blockDim.x + threadIdx.x;   // 0..1023
    float acc = echo[0];                              // f=0 (real)
    float nyq = echo[2 * 512];                        // Nyquist real part
    acc += (t & 1) ? -nyq : nyq;
    for (int f = 1; f < 512; f++) {
        int m = (f * t) & 1023;
        float ang = (float)m * 0.006135923151542565f;  // 2*pi/1024
        float s, c; __sincosf(ang, &s, &c);
        acc += 2.0f * (echo[2*f]*c - echo[2*f+1]*s);
    }
    acc *= (1.0f / 1024.0f);
    float tsec = (float)t * (1.0f / 16000.0f);
    float win = expf(LOG_GAMMA * tsec);
    out[t] = acc / win;
}

extern "C" void kernel_launch(void* const* d_in, const int* in_sizes, int n_in,
                              void* d_out, int out_size, void* d_ws, size_t ws_size,
                              hipStream_t stream) {
    const float* source_pos   = (const float*)d_in[0];
    const float* receiver_pos = (const float*)d_in[1];
    const float* absorption   = (const float*)d_in[2];
    const float* scattering   = (const float*)d_in[3];
    const float* gk_val       = (const float*)d_in[4];
    const float* basis        = (const float*)d_in[5];
    const float* avg_dist     = (const float*)d_in[6];
    const float* rpos         = (const float*)d_in[7];
    const int*   gk_row       = (const int*)d_in[8];
    const int*   gk_col       = (const int*)d_in[9];
    const int*   object_ids   = (const int*)d_in[10];
    float* out = (float*)d_out;

    char* base = (char*)d_ws;
    size_t off = 0;
    auto alloc = [&](size_t bytes) -> void* {
        void* ptr = base + off;
        off = (off + bytes + 255) & ~(size_t)255;
        return ptr;
    };
    const size_t PLANE = (size_t)RR * FP2 + FP2;   // +1 row slack for tail-tile overread
    float* Kt        = (float*)alloc(sizeof(float) * PP * DD * DD);
    float* cur       = (float*)alloc(sizeof(float) * PLANE);
    float* nxt       = (float*)alloc(sizeof(float) * PLANE);
    float* per_row   = (float*)alloc(sizeof(float) * 6 * RR);
    int*   counts    = (int*)alloc(sizeof(int) * RR);
    int*   row_start = (int*)alloc(sizeof(int) * (RR + 1));
    int*   cursor    = (int*)alloc(sizeof(int) * RR);
    int2*  edge      = (int2*)alloc(sizeof(int2) * EE);
    float* echo      = (float*)alloc(sizeof(float) * 1056);

    hipMemsetAsync(counts, 0, sizeof(int) * RR, stream);
    hipMemsetAsync(echo, 0, sizeof(float) * 1056, stream);

    k_per_row<<<RR / 256, 256, 0, stream>>>(rpos, source_pos, receiver_pos, avg_dist, per_row);
    k_build_Kt<<<(PP * DD * DD) / 256, 256, 0, stream>>>(absorption, scattering, object_ids, basis, Kt);
    k_count<<<EE / 256, 256, 0, stream>>>(gk_row, counts);
    k_scan<<<1, 1024, 0, stream>>>(counts, row_start, cursor);
    k_scatter<<<EE / 256, 256, 0, stream>>>(gk_row, gk_val, gk_col, cursor, edge);
    k_init<<<dim3(9, 32), 256, 0, stream>>>(per_row, cur, echo);

    for (int b = 0; b < 4; b++) {
        k_matmul<<<2176, 256, 0, stream>>>(Kt, cur, per_row, nxt);
        k_segsum<<<RR / 2, 512, 0, stream>>>(row_start, edge, nxt, cur);
        k_reduce<<<dim3(9, 32), 256, 0, stream>>>(cur, per_row, echo);
    }

    k_irfft<<<4, 256, 0, stream>>>(echo, out);
}

// Round 5
// 874.519 us; speedup vs baseline: 4.1305x; 1.2327x over previous
//
#include <hip/hip_runtime.h>
#include <math.h>

#define PP 128
#define DD 128
#define RR 16384
#define EE 131072
#define TT 1024
#define FF 513
#define FP 520          /* padded f count */
#define FP2 1040        /* floats per row (interleaved complex) */
#define KSTRIDE 132     /* LDS row stride for K tile: 16B-aligned, conflict-free */

#define TAU_SCALE 46.64723032069971    /* SR / C_SOUND */
#define KDECAY   -0.0211392282f        /* LOG_GAMMA/C - AIR */
#define LOG_GAMMA -6.907755278982137f
#define TWO_PI    6.283185307179586

__device__ __forceinline__ void pf_sincos(float tau, int f, float* s, float* c) {
    // phase = exp(-2*pi*i * tau * f / T); reduce in double, eval in float
    double rev = (double)tau * (double)f * (1.0 / 1024.0);
    rev -= floor(rev);
    float ang = (float)(-TWO_PI * rev);
    __sincosf(ang, s, c);
}

// ---- per-row precompute: amp_src, tau_src, amp_rec, tau_rec, dec_prop, tau_prop
__global__ void k_per_row(const float* __restrict__ rpos,
                          const float* __restrict__ spos,
                          const float* __restrict__ cpos,
                          const float* __restrict__ avg_dist,
                          float* __restrict__ per_row) {
    int r = blockIdx.x * blockDim.x + threadIdx.x;
    if (r >= RR) return;
    float x = rpos[3*r], y = rpos[3*r+1], z = rpos[3*r+2];

    float dx = x - spos[0], dy = y - spos[1], dz = z - spos[2];
    float ds = sqrtf(dx*dx + dy*dy + dz*dz);
    per_row[0*RR + r] = (1.0f/(ds*ds + 0.001f)) * expf(KDECAY * ds);
    per_row[1*RR + r] = ds * (float)TAU_SCALE;

    dx = x - cpos[0]; dy = y - cpos[1]; dz = z - cpos[2];
    float dr = sqrtf(dx*dx + dy*dy + dz*dz);
    per_row[2*RR + r] = (1.0f/(dr*dr + 0.001f)) * expf(KDECAY * dr);
    per_row[3*RR + r] = dr * (float)TAU_SCALE;

    float da = avg_dist[r];
    per_row[4*RR + r] = expf(KDECAY * da);
    per_row[5*RR + r] = da * (float)TAU_SCALE;
}

// ---- Kt[p][e][d] = refl*sc*basis0[d][e] + refl*(1-sc)*basis1[d][e]  (transposed)
__global__ void k_build_Kt(const float* __restrict__ absorption,
                           const float* __restrict__ scattering,
                           const int* __restrict__ object_ids,
                           const float* __restrict__ basis,
                           float* __restrict__ Kt) {
    int idx = blockIdx.x * 256 + threadIdx.x;   // p*16384 + e*128 + d
    int p = idx >> 14;
    int e = (idx >> 7) & 127;
    int d = idx & 127;
    int obj = object_ids[p];
    float refl = 1.0f - absorption[obj];
    float sc   = scattering[obj];
    int de = d * 128 + e;
    Kt[idx] = refl*sc*basis[de] + refl*(1.0f - sc)*basis[16384 + de];
}

// ---- CSR build
__global__ void k_count(const int* __restrict__ gk_row, int* __restrict__ counts) {
    int e = blockIdx.x * 256 + threadIdx.x;
    atomicAdd(&counts[gk_row[e]], 1);
}

__global__ __launch_bounds__(1024) void k_scan(const int* __restrict__ counts,
                                               int* __restrict__ row_start,
                                               int* __restrict__ cursor) {
    __shared__ int sh[1024];
    int tid = threadIdx.x;
    int base = tid * 16;
    int local[16];
    int sum = 0;
    #pragma unroll
    for (int j = 0; j < 16; j++) { local[j] = sum; sum += counts[base + j]; }
    sh[tid] = sum;
    __syncthreads();
    for (int off = 1; off < 1024; off <<= 1) {
        int v = (tid >= off) ? sh[tid - off] : 0;
        __syncthreads();
        sh[tid] += v;
        __syncthreads();
    }
    int chunk_excl = sh[tid] - sum;   // exclusive prefix of this 16-chunk
    #pragma unroll
    for (int j = 0; j < 16; j++) {
        int v = chunk_excl + local[j];
        row_start[base + j] = v;
        cursor[base + j] = v;
    }
    if (tid == 1023) row_start[RR] = chunk_excl + sum;
}

// scatter packing {col, val} per edge -> one b64 load in segsum
__global__ void k_scatter(const int* __restrict__ gk_row,
                          const float* __restrict__ gk_val,
                          const int* __restrict__ gk_col,
                          int* __restrict__ cursor,
                          int2* __restrict__ edge) {
    int e = blockIdx.x * 256 + threadIdx.x;
    int pos = atomicAdd(&cursor[gk_row[e]], 1);
    edge[pos] = make_int2(gk_col[e], __float_as_int(gk_val[e]));
}

// ---- init: cur[r][f] = amp_src*phase(tau_src); fused rad receiver-echo
__global__ __launch_bounds__(256) void k_init(const float* __restrict__ per_row,
                                              float* __restrict__ cur,
                                              float* __restrict__ echo) {
    int fl = threadIdx.x & 63, rg = threadIdx.x >> 6;
    int f = blockIdx.x * 64 + fl;               // < 576
    float ar = 0.f, ai = 0.f;
    int r0 = blockIdx.y * 128;
    if (f < FP) {
        for (int k = rg; k < 128; k += 4) {
            int r = r0 + k;
            float amp = per_row[r], tau = per_row[RR + r];
            float s, c; pf_sincos(tau, f, &s, &c);
            float re = amp * c, im = amp * s;
            *(float2*)(cur + (size_t)r * FP2 + f * 2) = make_float2(re, im);
            if (f < FF) {
                float w = per_row[2*RR + r], taur = per_row[3*RR + r];
                float s2, c2; pf_sincos(taur, f, &s2, &c2);
                ar = fmaf(w, c2*re - s2*im, ar);
                ai = fmaf(w, c2*im + s2*re, ai);
            }
        }
    }
    __shared__ float sh[4][64][2];
    sh[rg][fl][0] = ar; sh[rg][fl][1] = ai;
    __syncthreads();
    if (rg == 0 && f < FF) {
        float sx = sh[0][fl][0]+sh[1][fl][0]+sh[2][fl][0]+sh[3][fl][0];
        float sy = sh[0][fl][1]+sh[1][fl][1]+sh[2][fl][1]+sh[3][fl][1];
        atomicAdd(&echo[2*f],   sx);
        atomicAdd(&echo[2*f+1], sy);
    }
}

// ---- matmul + prop: out[p*128+d][f] = prop * sum_e Kt[p][e][d] * in[p*128+e][f]
// 1-D grid 2176 = 128 p x 17 ftiles(32 f), XCD-swizzled. 256 thr = 16 dg(8 d)
// x 16 fp(2 complex f). K staged in TWO 64-e chunks (LDS 33.8 KB -> 4 blk/CU).
// Inner loop per e: 2 LDS b128 (conflict-free broadcast) + 1 global dwordx4
// + 32 VALU FMA.
__global__ __launch_bounds__(256) void k_matmul(const float* __restrict__ Kt,
                                                const float* __restrict__ in,
                                                const float* __restrict__ per_row,
                                                float* __restrict__ out) {
    __shared__ float Klds[64 * KSTRIDE];   // [e-chunk][d]
    int b = blockIdx.x;
    int xcd = b & 7;
    int g = b >> 3;                 // 272 groups
    int p = (g / 17) * 8 + xcd;
    int ftile = g % 17;
    int tid = threadIdx.x;

    int fp = tid & 15;              // f-pair
    int dg = tid >> 4;              // 8-d group
    int f = (ftile << 5) + (fp << 1);
    const float* vbase = in + (size_t)(p << 7) * FP2 + f * 2;
    float acc[8][4];
    #pragma unroll
    for (int j = 0; j < 8; j++) { acc[j][0]=0.f; acc[j][1]=0.f; acc[j][2]=0.f; acc[j][3]=0.f; }
    const float* kbase = Klds + (dg << 3);

    for (int chunk = 0; chunk < 2; chunk++) {
        const float* Kp = Kt + (p << 14) + (chunk << 13);
        if (chunk) __syncthreads();           // protect readers of prev chunk
        for (int i = tid; i < 8192; i += 256)
            Klds[(i >> 7) * KSTRIDE + (i & 127)] = Kp[i];
        __syncthreads();
        const float* vb = vbase + (size_t)(chunk << 6) * FP2;
        #pragma unroll 4
        for (int ee = 0; ee < 64; ee++) {
            float4 v = *(const float4*)(vb + (size_t)ee * FP2);
            const float* kr = kbase + ee * KSTRIDE;
            #pragma unroll
            for (int j = 0; j < 8; j++) {
                float kv = kr[j];
                acc[j][0] = fmaf(kv, v.x, acc[j][0]);
                acc[j][1] = fmaf(kv, v.y, acc[j][1]);
                acc[j][2] = fmaf(kv, v.z, acc[j][2]);
                acc[j][3] = fmaf(kv, v.w, acc[j][3]);
            }
        }
    }
    if (f < FP) {                   // f<=518: stores f, f+1 both valid
        int d0 = dg << 3;
        #pragma unroll
        for (int j = 0; j < 8; j++) {
            int row = (p << 7) + d0 + j;
            float dec = per_row[4*RR + row];
            float tau = per_row[5*RR + row];
            float s0,c0,s1,c1;
            pf_sincos(tau, f,   &s0, &c0);
            pf_sincos(tau, f+1, &s1, &c1);
            float4 o;
            o.x = dec*(acc[j][0]*c0 - acc[j][1]*s0);
            o.y = dec*(acc[j][1]*c0 + acc[j][0]*s0);
            o.z = dec*(acc[j][2]*c1 - acc[j][3]*s1);
            o.w = dec*(acc[j][3]*c1 + acc[j][2]*s1);
            *(float4*)(out + (size_t)row * FP2 + f * 2) = o;
        }
    }
}

// ---- segment sum: cur[row][f] = sum_edges val*in[col][f]. 2 rows/block,
// 256 f-lanes, edges read once, 3 f-slices per edge (f, f+256, f+512<520).
__global__ __launch_bounds__(512) void k_segsum(const int* __restrict__ row_start,
                                                const int2* __restrict__ edge,
                                                const float* __restrict__ in,
                                                float* __restrict__ outp) {
    int ry = threadIdx.x >> 8;
    int row = (blockIdx.x << 1) + ry;
    int ft = threadIdx.x & 255;
    int s0 = row_start[row], s1 = row_start[row + 1];
    float a0r=0.f, a0i=0.f, a1r=0.f, a1i=0.f, a2r=0.f, a2i=0.f;
    bool has2 = (ft < 8);           // f2 = ft+512 < 520
    for (int t = s0; t < s1; t++) {
        int2 ed = edge[t];
        float v = __int_as_float(ed.y);
        const float* grow = in + (size_t)ed.x * FP2 + ft * 2;
        float2 g0 = *(const float2*)(grow);
        float2 g1 = *(const float2*)(grow + 512);
        a0r = fmaf(v, g0.x, a0r); a0i = fmaf(v, g0.y, a0i);
        a1r = fmaf(v, g1.x, a1r); a1i = fmaf(v, g1.y, a1i);
        if (has2) {
            float2 g2 = *(const float2*)(grow + 1024);
            a2r = fmaf(v, g2.x, a2r); a2i = fmaf(v, g2.y, a2i);
        }
    }
    float* wout = outp + (size_t)row * FP2 + ft * 2;
    *(float2*)(wout)       = make_float2(a0r, a0i);
    *(float2*)(wout + 512) = make_float2(a1r, a1i);
    if (has2) *(float2*)(wout + 1024) = make_float2(a2r, a2i);
}

// ---- per-bounce receiver reduction: echo[f] += sum_r w*phase(taur,f)*cur[r][f]
__global__ __launch_bounds__(256) void k_reduce(const float* __restrict__ plane,
                                                const float* __restrict__ per_row,
                                                float* __restrict__ echo) {
    int fl = threadIdx.x & 63, rg = threadIdx.x >> 6;
    int f = blockIdx.x * 64 + fl;
    bool act = (f < FF);
    float ar = 0.f, ai = 0.f;
    int r0 = blockIdx.y * 128;
    if (act) {
        for (int k = rg; k < 128; k += 4) {
            int r = r0 + k;
            float2 v = *(const float2*)(plane + (size_t)r * FP2 + f * 2);
            float w = per_row[2*RR + r], taur = per_row[3*RR + r];
            float s, c; pf_sincos(taur, f, &s, &c);
            ar = fmaf(w, c*v.x - s*v.y, ar);
            ai = fmaf(w, c*v.y + s*v.x, ai);
        }
    }
    __shared__ float sh[4][64][2];
    sh[rg][fl][0] = ar; sh[rg][fl][1] = ai;
    __syncthreads();
    if (rg == 0 && act) {
        float sx = sh[0][fl][0]+sh[1][fl][0]+sh[2][fl][0]+sh[3][fl][0];
        float sy = sh[0][fl][1]+sh[1][fl][1]+sh[2][fl][1]+sh[3][fl][1];
        atomicAdd(&echo[2*f],   sx);
        atomicAdd(&echo[2*f+1], sy);
    }
}

// ---- irfft(n=1024) / fsm_window
__global__ void k_irfft(const float* __restrict__ echo, float* __restrict__ out) {
    int t = blockIdx.x * blockDim.x + threadIdx.x;   // 0..1023
    float acc = echo[0];                              // f=0 (real)
    float nyq = echo[2 * 512];                        // Nyquist real part
    acc += (t & 1) ? -nyq : nyq;
    for (int f = 1; f < 512; f++) {
        int m = (f * t) & 1023;
        float ang = (float)m * 0.006135923151542565f;  // 2*pi/1024
        float s, c; __sincosf(ang, &s, &c);
        acc += 2.0f * (echo[2*f]*c - echo[2*f+1]*s);
    }
    acc *= (1.0f / 1024.0f);
    float tsec = (float)t * (1.0f / 16000.0f);
    float win = expf(LOG_GAMMA * tsec);
    out[t] = acc / win;
}

extern "C" void kernel_launch(void* const* d_in, const int* in_sizes, int n_in,
                              void* d_out, int out_size, void* d_ws, size_t ws_size,
                              hipStream_t stream) {
    const float* source_pos   = (const float*)d_in[0];
    const float* receiver_pos = (const float*)d_in[1];
    const float* absorption   = (const float*)d_in[2];
    const float* scattering   = (const float*)d_in[3];
    const float* gk_val       = (const float*)d_in[4];
    const float* basis        = (const float*)d_in[5];
    const float* avg_dist     = (const float*)d_in[6];
    const float* rpos         = (const float*)d_in[7];
    const int*   gk_row       = (const int*)d_in[8];
    const int*   gk_col       = (const int*)d_in[9];
    const int*   object_ids   = (const int*)d_in[10];
    float* out = (float*)d_out;

    char* base = (char*)d_ws;
    size_t off = 0;
    auto alloc = [&](size_t bytes) -> void* {
        void* ptr = base + off;
        off = (off + bytes + 255) & ~(size_t)255;
        return ptr;
    };
    const size_t PLANE = (size_t)RR * FP2 + FP2;   // +1 row slack for tail-tile overread
    float* Kt        = (float*)alloc(sizeof(float) * PP * DD * DD);
    float* cur       = (float*)alloc(sizeof(float) * PLANE);
    float* nxt       = (float*)alloc(sizeof(float) * PLANE);
    float* per_row   = (float*)alloc(sizeof(float) * 6 * RR);
    int*   counts    = (int*)alloc(sizeof(int) * RR);
    int*   row_start = (int*)alloc(sizeof(int) * (RR + 1));
    int*   cursor    = (int*)alloc(sizeof(int) * RR);
    int2*  edge      = (int2*)alloc(sizeof(int2) * EE);
    float* echo      = (float*)alloc(sizeof(float) * 1056);

    hipMemsetAsync(counts, 0, sizeof(int) * RR, stream);
    hipMemsetAsync(echo, 0, sizeof(float) * 1056, stream);

    k_per_row<<<RR / 256, 256, 0, stream>>>(rpos, source_pos, receiver_pos, avg_dist, per_row);
    k_build_Kt<<<(PP * DD * DD) / 256, 256, 0, stream>>>(absorption, scattering, object_ids, basis, Kt);
    k_count<<<EE / 256, 256, 0, stream>>>(gk_row, counts);
    k_scan<<<1, 1024, 0, stream>>>(counts, row_start, cursor);
    k_scatter<<<EE / 256, 256, 0, stream>>>(gk_row, gk_val, gk_col, cursor, edge);
    k_init<<<dim3(9, 128), 256, 0, stream>>>(per_row, cur, echo);

    for (int b = 0; b < 4; b++) {
        k_matmul<<<2176, 256, 0, stream>>>(Kt, cur, per_row, nxt);
        k_segsum<<<RR / 2, 512, 0, stream>>>(row_start, edge, nxt, cur);
        k_reduce<<<dim3(9, 128), 256, 0, stream>>>(cur, per_row, echo);
    }

    k_irfft<<<4, 256, 0, stream>>>(echo, out);
}